// Round 16
// baseline (256.884 us; speedup 1.0000x reference)
//
#include <hip/hip_runtime.h>
#include <hip/hip_bf16.h>
#include <math.h>

#define B_ 64
#define F_ 512   // feature dim = GEMM K
#define T_ 600
#define M_ 200   // merge_size = GEMM M and N
#define NFRAG 13 // 208 = 13*16 padded n-columns

typedef __attribute__((ext_vector_type(8))) short bf16x8_t;
typedef __attribute__((ext_vector_type(4))) float f32x4_t;

static __device__ __forceinline__ unsigned short f2bf(float v) {
    __hip_bfloat16 h = __float2bfloat16(v);
    return *reinterpret_cast<unsigned short*>(&h);
}
static __device__ __forceinline__ float bf2f(unsigned short u) {
    return __uint_as_float(((unsigned)u) << 16);
}

// ---------------------------------------------------------------------------
// Merge v5: (B,F,T) fp32 -> (B,F,M) bf16.  PURE STREAM: no LDS, no barrier.
// task = (row = b*F+f, j): reads floats 12j..12j+15, writes segments 4j..4j+3
// as one coalesced ushort4 (8B/lane).  4 unguarded tasks/thread.
// grid: (1600, 2), block 256.  Also zeroes out[0].
// ---------------------------------------------------------------------------
__global__ __launch_bounds__(256)
void merge_kernel(const float* __restrict__ a, const float* __restrict__ b,
                  unsigned short* __restrict__ fa, unsigned short* __restrict__ fb,
                  float* __restrict__ out) {
    if (blockIdx.x == 0 && blockIdx.y == 0 && threadIdx.x == 0) out[0] = 0.f;

    const float* src = (blockIdx.y == 0) ? a : b;
    unsigned short* dst = (blockIdx.y == 0) ? fa : fb;
    int t = threadIdx.x;
    int base = blockIdx.x * 1024;

    #pragma unroll
    for (int i = 0; i < 4; ++i) {
        int task = base + i * 256 + t;      // consecutive lanes -> consecutive j
        int row = task / 50;
        int j   = task - row * 50;
        const float4* rp = (const float4*)(src + (size_t)row * T_);
        float4 q0 = rp[3 * j];
        float4 q1 = rp[3 * j + 1];
        float4 q2 = rp[3 * j + 2];
        float4 q3 = (j < 49) ? rp[3 * j + 3] : rp[0];
        float s0 = q0.y + q0.z + q0.w;                    // m=4j+0: t=12j+1..3
        float s1 = q1.x + q1.y + q1.z;                    // m=4j+1
        float s2 = q1.w + q2.x + q2.y;                    // m=4j+2
        float s3 = (j < 49) ? (q2.z + q2.w + q3.x)        // m=4j+3: t=12j+10..12
                            : (q3.x + q2.z + q2.w);       // m=199: {0,598,599}
        ushort4 o;
        o.x = f2bf(s0); o.y = f2bf(s1); o.z = f2bf(s2); o.w = f2bf(s3);
        *(ushort4*)(dst + (size_t)row * M_ + 4 * j) = o;  // 8B-aligned
    }
}

// ---------------------------------------------------------------------------
// Norm v2: column L2-norms from (B,F,M) bf16.  Per block: one (b, tensor);
// stream 64 f-rows at a time into LDS (coalesced), accumulate per-m sumsq.
// grid: (B_, 2), block 256.
// ---------------------------------------------------------------------------
__global__ __launch_bounds__(256)
void norm_kernel(const unsigned short* __restrict__ fa, const unsigned short* __restrict__ fb,
                 float* __restrict__ na, float* __restrict__ nb) {
    const unsigned short* src = (blockIdx.y == 0) ? fa : fb;
    float*                dst = (blockIdx.y == 0) ? na : nb;
    int bb = blockIdx.x;
    int t  = threadIdx.x;
    __shared__ unsigned short lds[64][200];   // 25.6 KB

    const unsigned short* S = src + (size_t)bb * F_ * M_;
    float acc = 0.f;
    for (int f0 = 0; f0 < F_; f0 += 64) {
        // stage 64 rows x 200 ushorts = 1600 uint4, coalesced
        #pragma unroll
        for (int i = 0; i < 7; ++i) {
            int idx = t + i * 256;
            if (idx < 1600) {
                int r  = idx / 25;
                int c4 = idx - r * 25;
                *(uint4*)&lds[r][c4 * 8] =
                    *(const uint4*)(S + (size_t)(f0 + r) * M_ + c4 * 8);
            }
        }
        __syncthreads();
        if (t < M_) {
            #pragma unroll 16
            for (int f = 0; f < 64; ++f) {
                float x = bf2f(lds[f][t]);
                acc = fmaf(x, x, acc);
            }
        }
        __syncthreads();
    }
    if (t < M_) dst[bb * M_ + t] = sqrtf(acc);
}

// ---------------------------------------------------------------------------
// Fused: batched MFMA GEMM + cosine + row log-softmax + diag + loss.
// Source layout (B,F,M): staging reads f-rows (m-contiguous, coalesced) and
// register-transposes pairs of k into LDS via packed ds_write_b32
// (wave-uniform n-group -> <=2-way bank aliasing).  MFMA loop + epilogue
// unchanged from the R15-passing kernel; norms read from global.
// grid: (4, B_), block 256.
// ---------------------------------------------------------------------------
__global__ __launch_bounds__(256)
void fused_loss_kernel(const unsigned short* __restrict__ fa,
                       const unsigned short* __restrict__ fb,
                       const float* __restrict__ na_g,
                       const float* __restrict__ nb_g,
                       float* __restrict__ out) {
    __shared__ unsigned short As[64][88];    // [m][k] 11.3 KB
    __shared__ unsigned short Bs[208][88];   // [n][k] 36.6 KB
    __shared__ float wloss[4];

    int bb = blockIdx.y;
    int m0 = blockIdx.x * 64;
    const unsigned short* A  = fa + (size_t)bb * F_ * M_;
    const unsigned short* Bp = fb + (size_t)bb * F_ * M_;

    int t    = threadIdx.x;
    int lane = t & 63;
    int wave = t >> 6;
    int g    = lane >> 4;      // 0..3
    int c    = lane & 15;      // frag col

    f32x4_t acc[NFRAG];
    #pragma unroll
    for (int f = 0; f < NFRAG; ++f) acc[f] = (f32x4_t)(0.f);

    const uint4 z4 = make_uint4(0, 0, 0, 0);

    for (int k0 = 0; k0 < F_; k0 += 64) {
        // ---- stage A tile (64 m x 64 k): 1 task/thread ----
        {
            int flp = t & 31;            // k-pair index
            int mg  = t >> 5;            // 0..7 (8 m per group)
            bool mok = (m0 + 8 * mg + 8 <= M_);
            int f = k0 + 2 * flp;
            uint4 a0 = mok ? *(const uint4*)(A + (size_t)f       * M_ + m0 + 8 * mg) : z4;
            uint4 a1 = mok ? *(const uint4*)(A + (size_t)(f + 1) * M_ + m0 + 8 * mg) : z4;
            const unsigned short* s0 = (const unsigned short*)&a0;
            const unsigned short* s1 = (const unsigned short*)&a1;
            #pragma unroll
            for (int i = 0; i < 8; ++i) {
                unsigned pk = (unsigned)s0[i] | ((unsigned)s1[i] << 16);
                *(unsigned*)&As[8 * mg + i][2 * flp] = pk;
            }
        }
        // ---- stage B tile (208 n x 64 k): 832 tasks ----
        #pragma unroll
        for (int it = 0; it < 4; ++it) {
            int idx = t + it * 256;
            if (idx < 832) {
                int flp = idx & 31;
                int ng  = idx >> 5;       // 0..25
                bool nok = (ng < 25);     // rows 200..207 zero
                int f = k0 + 2 * flp;
                uint4 b0 = nok ? *(const uint4*)(Bp + (size_t)f       * M_ + 8 * ng) : z4;
                uint4 b1 = nok ? *(const uint4*)(Bp + (size_t)(f + 1) * M_ + 8 * ng) : z4;
                const unsigned short* s0 = (const unsigned short*)&b0;
                const unsigned short* s1 = (const unsigned short*)&b1;
                #pragma unroll
                for (int i = 0; i < 8; ++i) {
                    unsigned pk = (unsigned)s0[i] | ((unsigned)s1[i] << 16);
                    *(unsigned*)&Bs[8 * ng + i][2 * flp] = pk;
                }
            }
        }
        __syncthreads();
        #pragma unroll
        for (int kk = 0; kk < 2; ++kk) {
            int kc = kk * 32 + g * 8;
            bf16x8_t af = *(const bf16x8_t*)&As[wave * 16 + c][kc];
            #pragma unroll
            for (int f = 0; f < NFRAG; ++f) {
                bf16x8_t bfr = *(const bf16x8_t*)&Bs[f * 16 + c][kc];
                acc[f] = __builtin_amdgcn_mfma_f32_16x16x32_bf16(af, bfr, acc[f], 0, 0, 0);
            }
        }
        __syncthreads();
    }

    // ---- epilogue: cosine + row log-softmax + diag (m89 C/D layout) ----
    int m0w = m0 + wave * 16;
    float na_r[4];
    #pragma unroll
    for (int r = 0; r < 4; ++r) {
        int row = m0w + g * 4 + r;
        na_r[r] = (row < M_) ? na_g[bb * M_ + row] : 1.0f;
    }

    float mx[4] = {-INFINITY, -INFINITY, -INFINITY, -INFINITY};
    float diag_cos[4] = {0.f, 0.f, 0.f, 0.f};
    int f_diag = m0w >> 4;   // uniform per wave

    #pragma unroll
    for (int f = 0; f < NFRAG; ++f) {
        int col = f * 16 + c;
        bool colok = (col < M_);
        float nbv = colok ? nb_g[bb * M_ + col] : 1.0f;
        #pragma unroll
        for (int r = 0; r < 4; ++r) {
            float denom = fmaxf(na_r[r] * nbv, 1e-8f);
            float cv = acc[f][r] / denom;
            int row = m0w + g * 4 + r;
            if (f == f_diag && row < M_ && c == g * 4 + r) diag_cos[r] = cv;
            cv = colok ? cv : -INFINITY;
            acc[f][r] = cv;
            mx[r] = fmaxf(mx[r], cv);
        }
    }
    #pragma unroll
    for (int off = 1; off <= 8; off <<= 1)
        #pragma unroll
        for (int r = 0; r < 4; ++r)
            mx[r] = fmaxf(mx[r], __shfl_xor(mx[r], off, 64));

    float sm[4] = {0.f, 0.f, 0.f, 0.f};
    #pragma unroll
    for (int f = 0; f < NFRAG; ++f)
        #pragma unroll
        for (int r = 0; r < 4; ++r)
            sm[r] += __expf(acc[f][r] - mx[r]);   // -inf cols -> 0
    #pragma unroll
    for (int off = 1; off <= 8; off <<= 1)
        #pragma unroll
        for (int r = 0; r < 4; ++r)
            sm[r] += __shfl_xor(sm[r], off, 64);

    float loss = 0.f;
    #pragma unroll
    for (int r = 0; r < 4; ++r) {
        int row = m0w + g * 4 + r;
        if (row < M_ && c == g * 4 + r) {
            float lse = mx[r] + __logf(sm[r]);
            loss -= (diag_cos[r] - lse) * (1.0f / (float)M_);
        }
    }
    #pragma unroll
    for (int off = 1; off <= 32; off <<= 1)
        loss += __shfl_xor(loss, off, 64);
    if (lane == 0) wloss[wave] = loss;
    __syncthreads();
    if (t == 0) atomicAdd(out, wloss[0] + wloss[1] + wloss[2] + wloss[3]);
}

extern "C" void kernel_launch(void* const* d_in, const int* in_sizes, int n_in,
                              void* d_out, int out_size, void* d_ws, size_t ws_size,
                              hipStream_t stream) {
    // d_in[0] = data_label (int64) -- unused by the loss
    const float* a_in = (const float*)d_in[1];
    const float* b_in = (const float*)d_in[2];

    const size_t merged_elems = (size_t)B_ * F_ * M_;   // 6,553,600
    unsigned short* fa = (unsigned short*)d_ws;         // bf16 (B,F,M)
    unsigned short* fb = fa + merged_elems;
    float* na = (float*)(fb + merged_elems);            // B*M
    float* nb = na + B_ * M_;
    float* out = (float*)d_out;

    // 1. merge (pure stream, no LDS; also zeroes out[0])
    merge_kernel<<<dim3(1600, 2), 256, 0, stream>>>(a_in, b_in, fa, fb, out);
    // 2. column norms
    norm_kernel<<<dim3(B_, 2), 256, 0, stream>>>(fa, fb, na, nb);
    // 3. fused GEMM + cosine + log-softmax + diag + loss
    fused_loss_kernel<<<dim3(4, B_), 256, 0, stream>>>(fa, fb, na, nb, out);
}